// Round 9
// baseline (125.526 us; speedup 1.0000x reference)
//
#include <hip/hip_runtime.h>
#include <hip/hip_bf16.h>
#include <stdint.h>
#include <stddef.h>

// DistanceNetwork: sims[n,b] = dot(support[n], input[b]) * rsqrt(||support[n]||^2) * rsqrt(||input||_F^2)
//   support_set: [8192, 1024] fp32   input_image: [2048, 1024] fp32   out: [8192, 2048] fp32
#define M_DIM 8192
#define N_DIM 2048
#define K_DIM 1024

// R9 = R8 with the 8 per-iter barriers MERGED to 4 (phase pairs). R6's
// measured 9520 cyc/iter == MFMA floor (4966) + LDS floor (4608) SERIAL:
// 8 barriers/iter lockstep all waves into read-then-MFMA micro-phases, so
// the two pipes never overlap. Merging pairs lets waves drift within a
// 2-quadrant region -> cross-wave pipe overlap. Ledger re-derived:
//   VMW(8)@r1 drains SP4(0_i)   [2 regions old]
//   VMW(6)@r2 drains SP1-3(1_i) [1.5-2.5 regions old]
//   VMW(8)@r3 drains SP4(1_i)   [2 regions old]
//   VMW(6)@r4 drains SP1-3(0')  [1.5-2.5 regions old]
// Queue closure 10->8,12->6 per region, invariant closed. Every stage
// lands >=1 barrier after its region's last read-issue (same safety class
// as R3/R6/R8, all passed). prep and everything else byte-identical to R8.
#define BM 256
#define BN 256
#define BK 64
#define NKT (K_DIM / BK)  // 16 K-tiles
#define NITER (NKT / 2)   // 8 iterations (7 full + 1 tail)

typedef __attribute__((ext_vector_type(8))) short short8;   // 8 bf16 = 4 VGPRs
typedef __attribute__((ext_vector_type(8))) unsigned short ushort8v;  // 16B store
typedef __attribute__((ext_vector_type(4))) float float4v;  // MFMA C/D

// fp32 -> bf16 RNE
static __device__ __forceinline__ unsigned short f2bf(float x) {
  union { float f; unsigned u; } c; c.f = x;
  return (unsigned short)((c.u + 0x7FFFu + ((c.u >> 16) & 1u)) >> 16);
}

#define GLOAD_LDS16(g, l)                                           \
  __builtin_amdgcn_global_load_lds(                                 \
      (const __attribute__((address_space(1))) void*)(g),           \
      (__attribute__((address_space(3))) void*)(l), 16, 0, 0)

// ---------------- fused prep (v2, unchanged from R8) ----------------
__global__ __launch_bounds__(256) void prep(
    const float* __restrict__ S, const float* __restrict__ I,
    unsigned short* __restrict__ Sb, unsigned short* __restrict__ Ib,
    float* __restrict__ smag, float* __restrict__ partials) {
  const int t = threadIdx.x;
  const int lane = t & 63;
  const int wave = t >> 6;
  const int blk = blockIdx.x;
  const bool isS = blk < 2048;
  const int row = (isS ? blk : blk - 2048) * 4 + wave;
  const float4* s4 = reinterpret_cast<const float4*>((isS ? S : I) + (size_t)row * K_DIM);
  ushort8v* d8 = reinterpret_cast<ushort8v*>((isS ? Sb : Ib) + (size_t)row * K_DIM);

  float4 v[4];
  v[0] = s4[2 * lane];
  v[1] = s4[2 * lane + 1];
  v[2] = s4[128 + 2 * lane];
  v[3] = s4[128 + 2 * lane + 1];

  float ss = 0.f;
  ushort8v o0, o1;
#pragma unroll
  for (int h = 0; h < 2; ++h) {
    const float4 a = v[2 * h], b = v[2 * h + 1];
    ushort8v o;
    o[0] = f2bf(a.x); o[1] = f2bf(a.y); o[2] = f2bf(a.z); o[3] = f2bf(a.w);
    o[4] = f2bf(b.x); o[5] = f2bf(b.y); o[6] = f2bf(b.z); o[7] = f2bf(b.w);
    ss += a.x * a.x + a.y * a.y + a.z * a.z + a.w * a.w;
    ss += b.x * b.x + b.y * b.y + b.z * b.z + b.w * b.w;
    if (h == 0) o0 = o; else o1 = o;
  }
  d8[lane] = o0;
  d8[64 + lane] = o1;

#pragma unroll
  for (int m = 32; m >= 1; m >>= 1) ss += __shfl_xor(ss, m, 64);
  if (lane == 0) {
    if (isS) smag[row] = rsqrtf(fmaxf(ss, 1e-10f));
    else     partials[row] = ss;
  }
}

// ---------------- GEMM: 256^2, 4 merged regions/iter ----------------
// Region r: [stage SP][counted VMW][BARRIER][SGB chain]
//           [reads q_a | MFMA q_a-1-ish | stage | reads q_b | MFMA q_b]
// Same SP slots, read order, banks, VMW *targets* as R6 — only the
// barrier granularity and VMW counts changed (re-derived above).
__global__ __launch_bounds__(512, 2) void gemm_bt(
    const unsigned short* __restrict__ A,  // [M, K] bf16 (support)
    const unsigned short* __restrict__ B,  // [N, K] bf16 (input)
    const float* __restrict__ smag,        // [M]
    const float* __restrict__ partials,    // [2048] input-row sumsq partials
    float* __restrict__ C) {               // [M, N]
  __shared__ __align__(16) unsigned short lA[32768];  // 2 buf x 2 half x 8192
  __shared__ __align__(16) unsigned short lB[32768];
  __shared__ float wsum[8];

  const int t = threadIdx.x;     // 0..511
  const int lane = t & 63;
  const int wave = t >> 6;       // 0..7
  const int wr = wave >> 2;      // 0..1  (M half)
  const int wc = wave & 3;       // 0..3  (N quarter)

  // XCD swizzle: 256 blocks, 1/CU. Each XCD: 4 contiguous bm-tiles x 8 bn.
  const int blk = blockIdx.x;
  const int xcd = blk & 7;
  const int slot = blk >> 3;     // 0..31
  const int bm = (xcd * 4 + (slot & 3)) * BM;
  const int bn = (slot >> 2) * BN;

  // Input Frobenius-norm partials reduce. VMW(0) keeps vmcnt queue pure-stage.
  {
    float p = partials[t] + partials[t + 512] + partials[t + 1024] + partials[t + 1536];
#pragma unroll
    for (int m = 32; m >= 1; m >>= 1) p += __shfl_xor(p, m, 64);
    if (lane == 0) wsum[wave] = p;
  }
  asm volatile("s_waitcnt vmcnt(0)" ::: "memory");

  // Staging: thread t covers row-in-load = t>>3; stored chunk t&7 holds
  // logical kc = (t&7)^(row&7)  (XOR swizzle via pre-swizzled global src).
  const int srow = t >> 3;
  const int skc = (t & 7) ^ (srow & 7);
  const unsigned short* gA[4];   // loads j: tile rows [64j, 64j+64)
  const unsigned short* gB[4];
  int aoff[4];                   // LDS wave-uniform dest (shorts), per load j
#pragma unroll
  for (int j = 0; j < 4; ++j) {
    gA[j] = A + (size_t)(bm + j * 64 + srow) * K_DIM + skc * 8;
    gB[j] = B + (size_t)(bn + j * 64 + srow) * K_DIM + skc * 8;
    aoff[j] = (j >> 1) * 8192 + (j & 1) * 4096 + wave * 512;
  }

#define STAGE_A(j, buf) do { GLOAD_LDS16(gA[j], &lA[(buf) * 16384 + aoff[j]]); gA[j] += BK; } while (0)
#define STAGE_B(j, buf) do { GLOAD_LDS16(gB[j], &lB[(buf) * 16384 + aoff[j]]); gB[j] += BK; } while (0)
#define SP1(buf) do { STAGE_B(0, buf); STAGE_B(1, buf); } while (0)  // B rows 0-127
#define SP2(buf) do { STAGE_B(2, buf); STAGE_B(3, buf); } while (0)  // B rows 128-255
#define SP3(buf) do { STAGE_A(0, buf); STAGE_A(2, buf); } while (0)  // A mi 0-3 (both halves)
#define SP4(buf) do { STAGE_A(1, buf); STAGE_A(3, buf); } while (0)  // A mi 4-7 (both halves)

  // Fragment read bases (swizzled layout, 0 conflicts verified R1-R8).
  const int fr = lane & 15;
  const int q = lane >> 4;
  const int pc0 = (q ^ (fr & 7)) * 8;        // k-step s=0 chunk offset (shorts)
  const int pc1 = ((4 + q) ^ (fr & 7)) * 8;  // k-step s=1
  const unsigned short* rA = lA + wr * 8192 + fr * 64;
  const unsigned short* rB = lB + (wc >> 1) * 8192 + ((wc & 1) * 64 + fr) * 64;

  short8 af0[2][2], af1[2][2];   // A frag banks: [m2][s]
  short8 bfA[4][2], bfB[4][2];   // B frags per K-tile: [nj][s]
  float4v acc[8][4];
#pragma unroll
  for (int i = 0; i < 8; ++i)
#pragma unroll
    for (int j = 0; j < 4; ++j) acc[i][j] = (float4v)0.0f;

#define BARRIER() __builtin_amdgcn_s_barrier()
#define VMW(n) asm volatile("s_waitcnt vmcnt(" #n ")" ::: "memory")
#define PRIO1() __builtin_amdgcn_s_setprio(1)
#define PRIO0() __builtin_amdgcn_s_setprio(0)
// T19 pin for a merged region: r1 reads, 16 MFMA, r2 reads, 16 MFMA.
// LLVM SchedGroupMask: DS_READ=0x100, MFMA=0x8.
#define SGB2(r1, m1, r2, m2) do {                                              \
    __builtin_amdgcn_sched_group_barrier(0x100, r1, 0);                        \
    __builtin_amdgcn_sched_group_barrier(0x008, m1, 0);                        \
    __builtin_amdgcn_sched_group_barrier(0x100, r2, 0);                        \
    __builtin_amdgcn_sched_group_barrier(0x008, m2, 0);                        \
  } while (0)

#define LOADB_LO(bank, buf) do {                                               \
    _Pragma("unroll") for (int nj = 0; nj < 2; ++nj) {                         \
      bank[nj][0] = *reinterpret_cast<const short8*>(rB + (buf) * 16384 + nj * 1024 + pc0); \
      bank[nj][1] = *reinterpret_cast<const short8*>(rB + (buf) * 16384 + nj * 1024 + pc1); \
    } } while (0)

#define LOADB_HI(bank, buf) do {                                               \
    _Pragma("unroll") for (int nj = 2; nj < 4; ++nj) {                         \
      bank[nj][0] = *reinterpret_cast<const short8*>(rB + (buf) * 16384 + nj * 1024 + pc0); \
      bank[nj][1] = *reinterpret_cast<const short8*>(rB + (buf) * 16384 + nj * 1024 + pc1); \
    } } while (0)

#define LOADA(bank, buf, pi) do {                                              \
    _Pragma("unroll") for (int m2 = 0; m2 < 2; ++m2) {                         \
      bank[m2][0] = *reinterpret_cast<const short8*>(rA + (buf) * 16384 + ((pi) * 2 + m2) * 1024 + pc0); \
      bank[m2][1] = *reinterpret_cast<const short8*>(rA + (buf) * 16384 + ((pi) * 2 + m2) * 1024 + pc1); \
    } } while (0)

#define MFMA16(pi, abank, bbank) do {                                          \
    PRIO1();                                                                   \
    _Pragma("unroll") for (int m2 = 0; m2 < 2; ++m2)                           \
    _Pragma("unroll") for (int nj = 0; nj < 4; ++nj) {                         \
      acc[(pi) * 2 + m2][nj] = __builtin_amdgcn_mfma_f32_16x16x32_bf16(        \
          abank[m2][0], bbank[nj][0], acc[(pi) * 2 + m2][nj], 0, 0, 0);        \
      acc[(pi) * 2 + m2][nj] = __builtin_amdgcn_mfma_f32_16x16x32_bf16(        \
          abank[m2][1], bbank[nj][1], acc[(pi) * 2 + m2][nj], 0, 0, 0);        \
    } } while (0)

  // Full iteration: 4 merged regions (2 quadrants each).
#define ITER_F() do {                                                          \
    /* r1 (ph1+ph2) */                                                         \
    SP4(1); VMW(8);  BARRIER(); SGB2(8, 16, 4, 16);                            \
    LOADA(af1, 0, 1); LOADB_HI(bfA, 0); MFMA16(0, af0, bfA);                   \
    SP1(0); LOADA(af0, 0, 2); MFMA16(1, af1, bfA);                             \
    /* r2 (ph3+ph4) */                                                         \
    SP2(0); VMW(6);  BARRIER(); SGB2(4, 16, 8, 16);                            \
    LOADA(af1, 0, 3); MFMA16(2, af0, bfA);                                     \
    SP3(0); LOADB_LO(bfB, 1); LOADA(af0, 1, 0); MFMA16(3, af1, bfA);           \
    /* r3 (ph5+ph6) */                                                         \
    SP4(0); VMW(8);  BARRIER(); SGB2(8, 16, 4, 16);                            \
    LOADA(af1, 1, 1); LOADB_HI(bfB, 1); MFMA16(0, af0, bfB);                   \
    SP1(1); LOADA(af0, 1, 2); MFMA16(1, af1, bfB);                             \
    /* r4 (ph7+ph8) */                                                         \
    SP2(1); VMW(6);  BARRIER(); SGB2(4, 16, 8, 16);                            \
    LOADA(af1, 1, 3); MFMA16(2, af0, bfB);                                     \
    SP3(1); LOADB_LO(bfA, 0); LOADA(af0, 0, 0); MFMA16(3, af1, bfB);           \
  } while (0)

  // Tail iteration: only T15.A-hi staged (r1 head); drains VMW(8)/(2)/(0).
#define ITER_T() do {                                                          \
    /* r1 */                                                                   \
    SP4(1); VMW(8);  BARRIER(); SGB2(8, 16, 4, 16);                            \
    LOADA(af1, 0, 1); LOADB_HI(bfA, 0); MFMA16(0, af0, bfA);                   \
    LOADA(af0, 0, 2); MFMA16(1, af1, bfA);                                     \
    /* r2 */                                                                   \
    VMW(2);          BARRIER(); SGB2(4, 16, 8, 16);                            \
    LOADA(af1, 0, 3); MFMA16(2, af0, bfA);                                     \
    LOADB_LO(bfB, 1); LOADA(af0, 1, 0); MFMA16(3, af1, bfA);                   \
    /* r3 */                                                                   \
    VMW(0);          BARRIER(); SGB2(8, 16, 4, 16);                            \
    LOADA(af1, 1, 1); LOADB_HI(bfB, 1); MFMA16(0, af0, bfB);                   \
    LOADA(af0, 1, 2); MFMA16(1, af1, bfB);                                     \
    /* r4 */                                                                   \
                     BARRIER();                                                \
    __builtin_amdgcn_sched_group_barrier(0x100, 4, 0);                         \
    __builtin_amdgcn_sched_group_barrier(0x008, 32, 0);                        \
    LOADA(af1, 1, 3); MFMA16(2, af0, bfB);                                     \
    MFMA16(3, af1, bfB);                                                       \
  } while (0)

  // Prologue (unchanged): stage T0 fully + T1.{B,A-lo}; VMW(6) drains T0;
  // barrier publishes staging + wsum; preload r1 operands (full bfA + af0).
  SP1(0); SP2(0); SP3(0); SP4(0);   // T0 complete
  SP1(1); SP2(1); SP3(1);           // T1 minus A-hi
  VMW(6);                           // T0 drained; [S1,S2,S3](T1) in flight
  BARRIER();
  LOADB_LO(bfA, 0); LOADB_HI(bfA, 0); LOADA(af0, 0, 0);

#pragma unroll 1
  for (int it = 0; it < NITER - 1; ++it) ITER_F();
  ITER_T();

  // Epilogue: C/D layout col = lane&15, row = (lane>>4)*4 + reg
  const float imag = rsqrtf(fmaxf(wsum[0] + wsum[1] + wsum[2] + wsum[3] +
                                  wsum[4] + wsum[5] + wsum[6] + wsum[7], 1e-10f));
#pragma unroll
  for (int mi = 0; mi < 8; ++mi) {
    const int rbase = bm + wr * 128 + mi * 16 + q * 4;
#pragma unroll
    for (int r = 0; r < 4; ++r) {
      const int row = rbase + r;
      const float sc = smag[row] * imag;
      float* crow = C + (size_t)row * N_DIM + bn + wc * 64 + fr;
#pragma unroll
      for (int nj = 0; nj < 4; ++nj) crow[nj * 16] = acc[mi][nj][r] * sc;
    }
  }
}

// ---------------- launch ----------------
extern "C" void kernel_launch(void* const* d_in, const int* in_sizes, int n_in,
                              void* d_out, int out_size, void* d_ws, size_t ws_size,
                              hipStream_t stream) {
  const float* S = (const float*)d_in[0];  // support_set [8192,1024]
  const float* I = (const float*)d_in[1];  // input_image [2048,1024]
  float* out = (float*)d_out;

  // ws layout: Sb bf16 16MB | Ib bf16 4MB | smag 32KB | partials 8KB
  unsigned char* ws = (unsigned char*)d_ws;
  unsigned short* Sb = (unsigned short*)ws;
  unsigned short* Ib = (unsigned short*)(ws + (size_t)M_DIM * K_DIM * 2);
  float* smag = (float*)(ws + (size_t)M_DIM * K_DIM * 2 + (size_t)N_DIM * K_DIM * 2);
  float* partials = smag + M_DIM;

  hipLaunchKernelGGL(prep, dim3(2560), dim3(256), 0, stream,
                     S, I, Sb, Ib, smag, partials);
  hipLaunchKernelGGL(gemm_bt, dim3((M_DIM / BM) * (N_DIM / BN)), dim3(512), 0, stream,
                     Sb, Ib, smag, partials, out);
}